// Round 2
// baseline (416.741 us; speedup 1.0000x reference)
//
#include <hip/hip_runtime.h>

// SCAM fused kernel for MI355X (gfx950).
// One block per (b,h) slice; everything per-slice is 128x128.
// bf16 MFMA (16x16x32) for all 7 matmuls; dual softmax fused; fp32 outputs.

typedef __attribute__((ext_vector_type(8))) __bf16 bf16x8;
typedef __attribute__((ext_vector_type(4))) __bf16 bf16x4;
typedef __attribute__((ext_vector_type(4))) float f4;

#define MFMA(A, B, C) __builtin_amdgcn_mfma_f32_16x16x32_bf16((A), (B), (C), 0, 0, 0)
#define SCALE_QK 0.08838834764831845f  // 128^-0.5

// XOR-swizzled LDS offset for a [128][128] bf16 slot (256 B row stride, no pad).
// Elements addressed in 8-element (16 B) blocks; block index xored with (n&7)
// -> b128 reads across 16 consecutive n hit distinct bank groups (<=2-way).
static __device__ __forceinline__ int eoff(int n, int k) {
  return (n << 8) + ((((k >> 3) ^ (n & 7)) << 4) | ((k & 7) << 1));
}

// Prep: transpose 4 fp32 [k][n] weight matrices to bf16 [n][k] in workspace.
__global__ void prep_w(const float* __restrict__ w0, const float* __restrict__ w1,
                       const float* __restrict__ w2, const float* __restrict__ w3,
                       __bf16* __restrict__ out) {
  int m = blockIdx.y;
  const float* src = (m == 0) ? w0 : (m == 1) ? w1 : (m == 2) ? w2 : w3;
  int t = blockIdx.x * 256 + threadIdx.x;  // 0..16383
  int k = t >> 7, n = t & 127;
  out[m * 16384 + n * 128 + k] = (__bf16)src[k * 128 + n];
}

// Stage one bf16 [n][128] weight matrix from global into a swizzled LDS slot.
static __device__ __forceinline__ void stage_w(char* slot, const __bf16* __restrict__ wTm,
                                               int tid) {
#pragma unroll
  for (int it = 0; it < 8; ++it) {
    int idx = it * 256 + tid;      // 2048 x 16B chunks
    int n = idx >> 4, seg = idx & 15;
    uint4 v = *(const uint4*)(wTm + n * 128 + seg * 8);
    *(uint4*)(slot + (n << 8) + ((seg ^ (n & 7)) << 4)) = v;
  }
}

// Load one side's 128x128 fp32 tile, compute LayerNorm, and return both the
// raw x and ln(x) as per-wave register-resident MFMA A-fragments (bf16).
static __device__ __forceinline__ void load_side(
    const float* __restrict__ xp, size_t base, const float* __restrict__ g,
    const float* __restrict__ b, char* xs, char* ls, int w, int lane, int l16, int quad,
    bf16x8* xF, bf16x8* lF) {
  int half = lane >> 5;
  int c4 = (lane & 31) << 2;
  float4 gv = *(const float4*)(g + c4);
  float4 bv = *(const float4*)(b + c4);
#pragma unroll
  for (int i = 0; i < 16; ++i) {
    int row = w * 32 + i * 2 + half;   // wave owns rows [32w, 32w+32)
    float4 xv = *(const float4*)(xp + base + row * 128 + c4);
    float s = xv.x + xv.y + xv.z + xv.w;
    float s2 = xv.x * xv.x + xv.y * xv.y + xv.z * xv.z + xv.w * xv.w;
#pragma unroll
    for (int d = 1; d < 32; d <<= 1) {  // reduce across the 32-lane half
      s += __shfl_xor(s, d);
      s2 += __shfl_xor(s2, d);
    }
    float mean = s * 0.0078125f;
    float var = s2 * 0.0078125f - mean * mean;
    float rstd = rsqrtf(var + 1e-6f);
    bf16x4 xu, lu;
    xu[0] = (__bf16)xv.x; xu[1] = (__bf16)xv.y; xu[2] = (__bf16)xv.z; xu[3] = (__bf16)xv.w;
    lu[0] = (__bf16)((xv.x - mean) * rstd * gv.x + bv.x);
    lu[1] = (__bf16)((xv.y - mean) * rstd * gv.y + bv.y);
    lu[2] = (__bf16)((xv.z - mean) * rstd * gv.z + bv.z);
    lu[3] = (__bf16)((xv.w - mean) * rstd * gv.w + bv.w);
    int off = eoff(row, c4);
    *(bf16x4*)(xs + off) = xu;
    *(bf16x4*)(ls + off) = lu;
  }
  __syncthreads();
#pragma unroll
  for (int mt = 0; mt < 2; ++mt)
#pragma unroll
    for (int ks = 0; ks < 4; ++ks) {
      int row = w * 32 + mt * 16 + l16, k = ks * 32 + quad * 8;
      xF[mt * 4 + ks] = *(const bf16x8*)(xs + eoff(row, k));
      lF[mt * 4 + ks] = *(const bf16x8*)(ls + eoff(row, k));
    }
  __syncthreads();
}

// Projection: out = A @ W + bias, A from register fragments, W from LDS slot.
// TRANSPOSED=0: write out row-major [row][col] (for q_l/q_r; scale applied).
// TRANSPOSED=1: write out transposed  [col][row] (for v_l/v_r B-operands).
template <int TRANSPOSED>
static __device__ __forceinline__ void proj(const bf16x8* aF, const char* wslot, char* dst,
                                            const float* __restrict__ bias, float scale,
                                            int w, int l16, int quad) {
#pragma unroll
  for (int nt = 0; nt < 8; ++nt) {
    f4 a0 = {0.f, 0.f, 0.f, 0.f}, a1 = {0.f, 0.f, 0.f, 0.f};
#pragma unroll
    for (int ks = 0; ks < 4; ++ks) {
      bf16x8 bf = *(const bf16x8*)(wslot + eoff(nt * 16 + l16, ks * 32 + quad * 8));
      a0 = MFMA(aF[ks], bf, a0);
      a1 = MFMA(aF[4 + ks], bf, a1);
    }
    float bs = bias[nt * 16 + l16];
    if (TRANSPOSED) {
      int c = nt * 16 + l16;
#pragma unroll
      for (int mt = 0; mt < 2; ++mt) {
        f4 a = mt ? a1 : a0;
        bf16x4 v;
#pragma unroll
        for (int r = 0; r < 4; ++r) v[r] = (__bf16)((a[r] + bs) * scale);
        *(bf16x4*)(dst + eoff(c, w * 32 + mt * 16 + quad * 4)) = v;
      }
    } else {
#pragma unroll
      for (int mt = 0; mt < 2; ++mt) {
        f4 a = mt ? a1 : a0;
#pragma unroll
        for (int r = 0; r < 4; ++r) {
          int i = w * 32 + mt * 16 + quad * 4 + r;
          *(__bf16*)(dst + eoff(i, nt * 16 + l16)) = (__bf16)((a[r] + bs) * scale);
        }
      }
    }
  }
}

// f = P @ V : P from register A-fragments, V^T from LDS slot; f -> LDS row-major.
static __device__ __forceinline__ void pv(const bf16x8* pF, const char* vslot, char* fdst,
                                          int w, int l16, int quad) {
#pragma unroll
  for (int nt = 0; nt < 8; ++nt) {
    f4 a0 = {0.f, 0.f, 0.f, 0.f}, a1 = {0.f, 0.f, 0.f, 0.f};
#pragma unroll
    for (int ks = 0; ks < 4; ++ks) {
      bf16x8 bf = *(const bf16x8*)(vslot + eoff(nt * 16 + l16, ks * 32 + quad * 8));
      a0 = MFMA(pF[ks], bf, a0);
      a1 = MFMA(pF[4 + ks], bf, a1);
    }
#pragma unroll
    for (int mt = 0; mt < 2; ++mt) {
      f4 a = mt ? a1 : a0;
#pragma unroll
      for (int r = 0; r < 4; ++r) {
        int i = w * 32 + mt * 16 + quad * 4 + r;
        *(__bf16*)(fdst + eoff(i, nt * 16 + l16)) = (__bf16)a[r];
      }
    }
  }
}

// out = x + scl[c] * f, coalesced; fp32 store (reference output dtype).
static __device__ __forceinline__ void epilogue(const float* __restrict__ xp, size_t base,
                                                const float* __restrict__ scl,
                                                const char* fsrc, float* __restrict__ outp,
                                                int tid) {
#pragma unroll
  for (int it = 0; it < 16; ++it) {
    int idx = it * 256 + tid;
    int row = idx >> 5, cb = (idx & 31) << 2;
    float4 xv = *(const float4*)(xp + base + row * 128 + cb);
    float4 sv = *(const float4*)(scl + cb);
    bf16x4 fu = *(const bf16x4*)(fsrc + eoff(row, cb));
    float4 ov;
    ov.x = xv.x + sv.x * (float)fu[0];
    ov.y = xv.y + sv.y * (float)fu[1];
    ov.z = xv.z + sv.z * (float)fu[2];
    ov.w = xv.w + sv.w * (float)fu[3];
    *(float4*)(outp + base + row * 128 + cb) = ov;
  }
}

__global__ __launch_bounds__(256, 2) void scam_fused(
    const float* __restrict__ xl, const float* __restrict__ xr,
    const float* __restrict__ gl, const float* __restrict__ bl,
    const float* __restrict__ gr, const float* __restrict__ br,
    const __bf16* __restrict__ wT,  // 4 x [128][128] bf16, order: ql, qr, vl, vr
    const float* __restrict__ bql, const float* __restrict__ bqr,
    const float* __restrict__ bvl, const float* __restrict__ bvr,
    const float* __restrict__ beta, const float* __restrict__ gamma,
    float* __restrict__ out0, float* __restrict__ out1) {
  __shared__ char smem[65536];
  char* S1 = smem;           // 32 KB slot
  char* S2 = smem + 32768;   // 32 KB slot
  int tid = threadIdx.x;
  int lane = tid & 63, w = tid >> 6;
  int quad = lane >> 4, l16 = lane & 15;
  size_t base = (size_t)blockIdx.x << 14;  // bh * 128*128

  // ---- Phase 0: load x_l/x_r, LayerNorm, register A-fragments ----
  bf16x8 xlF[8], llF[8], xrF[8], lrF[8];
  load_side(xl, base, gl, bl, S1, S2, w, lane, l16, quad, xlF, llF);
  load_side(xr, base, gr, br, S1, S2, w, lane, l16, quad, xrF, lrF);

  // ---- Phase 1: q_l = (ln_l @ Wql + b) * SCALE -> S2, then A-frags ----
  stage_w(S1, wT, tid);
  __syncthreads();
  proj<0>(llF, S1, S2, bql, SCALE_QK, w, l16, quad);
  __syncthreads();
  bf16x8 qlF[8];
#pragma unroll
  for (int mt = 0; mt < 2; ++mt)
#pragma unroll
    for (int ks = 0; ks < 4; ++ks)
      qlF[mt * 4 + ks] =
          *(const bf16x8*)(S2 + eoff(w * 32 + mt * 16 + l16, ks * 32 + quad * 8));
  __syncthreads();

  // ---- Phase 2: q_r = ln_r @ Wqr + b -> S2 (row-major [j][c]) ----
  stage_w(S1, wT + 16384, tid);
  __syncthreads();
  proj<0>(lrF, S1, S2, bqr, 1.0f, w, l16, quad);
  __syncthreads();

  // ---- Phase 3: S = q_l @ q_r^T (K = c), rows owned per-wave ----
  f4 sacc[2][8];
  const f4 fzero = {0.f, 0.f, 0.f, 0.f};
#pragma unroll
  for (int mt = 0; mt < 2; ++mt)
#pragma unroll
    for (int nt = 0; nt < 8; ++nt) sacc[mt][nt] = fzero;
#pragma unroll
  for (int nt = 0; nt < 8; ++nt)
#pragma unroll
    for (int ks = 0; ks < 4; ++ks) {
      bf16x8 bf = *(const bf16x8*)(S2 + eoff(nt * 16 + l16, ks * 32 + quad * 8));
      sacc[0][nt] = MFMA(qlF[ks], bf, sacc[0][nt]);
      sacc[1][nt] = MFMA(qlF[4 + ks], bf, sacc[1][nt]);
    }

  // ---- Phase 4: dual softmax ----
  // Row stats: row r lives in one quad (16 lanes x 8 cols each).
  float rm[2][4], rinv[2][4];
#pragma unroll
  for (int mt = 0; mt < 2; ++mt)
#pragma unroll
    for (int r = 0; r < 4; ++r) {
      float m = -1e30f;
#pragma unroll
      for (int nt = 0; nt < 8; ++nt) m = fmaxf(m, sacc[mt][nt][r]);
#pragma unroll
      for (int d = 1; d < 16; d <<= 1) m = fmaxf(m, __shfl_xor(m, d));
      float s = 0.f;
#pragma unroll
      for (int nt = 0; nt < 8; ++nt) s += __expf(sacc[mt][nt][r] - m);
#pragma unroll
      for (int d = 1; d < 16; d <<= 1) s += __shfl_xor(s, d);
      rm[mt][r] = m;
      rinv[mt][r] = 1.f / s;
    }
  // Col stats: quad shuffles then cross-wave via 2 KB scratch overlaid on S1.
  float* colred = (float*)S1;
  float cm[8], cinv[8];
#pragma unroll
  for (int nt = 0; nt < 8; ++nt) {
    float m = -1e30f;
#pragma unroll
    for (int mt = 0; mt < 2; ++mt)
#pragma unroll
      for (int r = 0; r < 4; ++r) m = fmaxf(m, sacc[mt][nt][r]);
    m = fmaxf(m, __shfl_xor(m, 16));
    m = fmaxf(m, __shfl_xor(m, 32));
    cm[nt] = m;
  }
  __syncthreads();  // all waves past S-mfma (S1/S2 reads done)
  if (quad == 0) {
#pragma unroll
    for (int nt = 0; nt < 8; ++nt) colred[w * 128 + nt * 16 + l16] = cm[nt];
  }
  __syncthreads();
#pragma unroll
  for (int nt = 0; nt < 8; ++nt) {
    float m = cm[nt];
#pragma unroll
    for (int ww = 0; ww < 4; ++ww) m = fmaxf(m, colred[ww * 128 + nt * 16 + l16]);
    cm[nt] = m;
  }
  __syncthreads();
#pragma unroll
  for (int nt = 0; nt < 8; ++nt) {
    float s = 0.f;
#pragma unroll
    for (int mt = 0; mt < 2; ++mt)
#pragma unroll
      for (int r = 0; r < 4; ++r) s += __expf(sacc[mt][nt][r] - cm[nt]);
    s += __shfl_xor(s, 16);
    s += __shfl_xor(s, 32);
    cinv[nt] = s;  // wave-local column sum
  }
  if (quad == 0) {
#pragma unroll
    for (int nt = 0; nt < 8; ++nt) colred[w * 128 + nt * 16 + l16] = cinv[nt];
  }
  __syncthreads();
#pragma unroll
  for (int nt = 0; nt < 8; ++nt) {
    float s = 0.f;
#pragma unroll
    for (int ww = 0; ww < 4; ++ww) s += colred[ww * 128 + nt * 16 + l16];
    cinv[nt] = 1.f / s;
  }
  __syncthreads();  // colred done; S1 free

  // P_r (row-softmax) -> S1 [i][j]; P_c^T (col-softmax, transposed) -> S2 [i][j].
#pragma unroll
  for (int mt = 0; mt < 2; ++mt)
#pragma unroll
    for (int nt = 0; nt < 8; ++nt) {
      bf16x4 pc;
#pragma unroll
      for (int r = 0; r < 4; ++r) {
        float sv = sacc[mt][nt][r];
        int i = w * 32 + mt * 16 + quad * 4 + r;
        *(__bf16*)(S1 + eoff(i, nt * 16 + l16)) =
            (__bf16)(__expf(sv - rm[mt][r]) * rinv[mt][r]);
        pc[r] = (__bf16)(__expf(sv - cm[nt]) * cinv[nt]);
      }
      *(bf16x4*)(S2 + eoff(nt * 16 + l16, w * 32 + mt * 16 + quad * 4)) = pc;
    }
  __syncthreads();
  bf16x8 prF[8], pcF[8];
#pragma unroll
  for (int mt = 0; mt < 2; ++mt)
#pragma unroll
    for (int ks = 0; ks < 4; ++ks) {
      int row = w * 32 + mt * 16 + l16, k = ks * 32 + quad * 8;
      prF[mt * 4 + ks] = *(const bf16x8*)(S1 + eoff(row, k));
      pcF[mt * 4 + ks] = *(const bf16x8*)(S2 + eoff(row, k));
    }
  __syncthreads();

  // ---- Phase 5/6: v_r -> S2 (transposed), f_r2l -> S1, out0 ----
  stage_w(S1, wT + 3 * 16384, tid);  // w_vr
  __syncthreads();
  proj<1>(xrF, S1, S2, bvr, 1.0f, w, l16, quad);
  __syncthreads();
  pv(prF, S2, S1, w, l16, quad);
  __syncthreads();
  epilogue(xl, base, beta, S1, out0, tid);
  __syncthreads();

  // ---- Phase 7/8: v_l -> S2 (transposed), f_l2r -> S1, out1 ----
  stage_w(S1, wT + 2 * 16384, tid);  // w_vl
  __syncthreads();
  proj<1>(xlF, S1, S2, bvl, 1.0f, w, l16, quad);
  __syncthreads();
  pv(pcF, S2, S1, w, l16, quad);
  __syncthreads();
  epilogue(xr, base, gamma, S1, out1, tid);
}

extern "C" void kernel_launch(void* const* d_in, const int* in_sizes, int n_in,
                              void* d_out, int out_size, void* d_ws, size_t ws_size,
                              hipStream_t stream) {
  const float* xl = (const float*)d_in[0];
  const float* xr = (const float*)d_in[1];
  const float* gl = (const float*)d_in[2];
  const float* bl = (const float*)d_in[3];
  const float* gr = (const float*)d_in[4];
  const float* br = (const float*)d_in[5];
  const float* wql = (const float*)d_in[6];
  const float* bql = (const float*)d_in[7];
  const float* wqr = (const float*)d_in[8];
  const float* bqr = (const float*)d_in[9];
  const float* wvl = (const float*)d_in[10];
  const float* bvl = (const float*)d_in[11];
  const float* wvr = (const float*)d_in[12];
  const float* bvr = (const float*)d_in[13];
  const float* beta = (const float*)d_in[14];
  const float* gamma = (const float*)d_in[15];

  __bf16* wT = (__bf16*)d_ws;          // 4 * 16384 bf16 = 128 KB scratch
  float* out0 = (float*)d_out;         // [8,128,128,128] fp32
  float* out1 = out0 + (size_t)8 * 128 * 128 * 128;

  prep_w<<<dim3(64, 4), 256, 0, stream>>>(wql, wqr, wvl, wvr, wT);
  scam_fused<<<1024, 256, 0, stream>>>(xl, xr, gl, bl, gr, br, wT, bql, bqr, bvl, bvr,
                                       beta, gamma, out0, out1);
}